// Round 2
// baseline (250.826 us; speedup 1.0000x reference)
//
#include <hip/hip_runtime.h>

// YOLO loss reduction: B=512, 3136 cells/sample, 15 slots/cell, fp32.
// R1 post-mortem: LDS-staging version was latency-bound (HBM 16%, VALU 8%,
// occupancy 34%) — per-tile barrier forces vmcnt(0) drain, serializing 6
// HBM round-trips per block.
//
// R2: barrier-free. 4 cells = 60 floats = exactly 15 float4s, so each thread
// owns 4 consecutive cells via 30 independent unrolled float4 loads (o + t).
// Latency hidden by per-thread ILP (~30 loads in flight), not barriers.
// Lane stride 240 B amplifies L1<->L2 traffic ~4x, but the L2 ceiling for
// that (~771 MB @ 34.5 TB/s ~= 22 us) is below the HBM/L3 floor -> doesn't bind.

#define EPSF 1e-9f

__global__ __launch_bounds__(256) void yolo_loss_kernel(
    const float* __restrict__ o, const float* __restrict__ t,
    float* __restrict__ out_sum, int n_cells)
{
    const int tid = threadIdx.x;
    const int g   = blockIdx.x * 256 + tid;   // 4-cell group id
    const int n_groups = n_cells >> 2;

    float acc = 0.f;

    if (g < n_groups) {
        const float4* o4 = (const float4*)o + (size_t)g * 15;
        const float4* t4 = (const float4*)t + (size_t)g * 15;

        float4 ob[15], tb[15];
        #pragma unroll
        for (int j = 0; j < 15; ++j) { ob[j] = o4[j]; tb[j] = t4[j]; }
        const float* os = (const float*)ob;
        const float* ts = (const float*)tb;

        float csum[4], x0[4];
        #pragma unroll
        for (int c = 0; c < 4; ++c) {
            const float* oc = os + c * 15;
            const float* tc = ts + c * 15;
            x0[c] = oc[0];
            const float d0 = oc[0] - tc[0];
            const float dw = sqrtf(oc[2]) - sqrtf(tc[2]);
            const float dh = sqrtf(oc[3]) - sqrtf(tc[3]);
            const float tv = tc[4], ov = oc[4];
            const float conf = -(tv * __logf(ov + EPSF)
                               + (1.f - tv) * __logf(1.f - ov + EPSF));
            float s = d0 * d0 + dw * dw + dh * dh + conf;
            #pragma unroll
            for (int k = 5; k < 14; ++k) {
                const float d = tc[k] - oc[k];
                s += d * d;
            }
            csum[c] = s;
        }
        #pragma unroll
        for (int c = 0; c < 4; ++c)
            acc += (x0[c] != 0.f) ? csum[c] : 0.f;
    }

    // Tail cells (n_cells % 4), handled scalar by the first few threads of the grid.
    const int tail_base = n_groups << 2;
    const int n_tail = n_cells - tail_base;
    if (blockIdx.x == 0 && tid < n_tail) {
        const float* oc = o + (size_t)(tail_base + tid) * 15;
        const float* tc = t + (size_t)(tail_base + tid) * 15;
        const float o0 = oc[0];
        if (o0 != 0.f) {
            const float d0 = o0 - tc[0];
            const float dw = sqrtf(oc[2]) - sqrtf(tc[2]);
            const float dh = sqrtf(oc[3]) - sqrtf(tc[3]);
            const float tv = tc[4], ov = oc[4];
            const float conf = -(tv * __logf(ov + EPSF)
                               + (1.f - tv) * __logf(1.f - ov + EPSF));
            float s = d0 * d0 + dw * dw + dh * dh + conf;
            #pragma unroll
            for (int k = 5; k < 14; ++k) {
                const float d = tc[k] - oc[k];
                s += d * d;
            }
            acc += s;
        }
    }

    // wave (64-lane) shuffle reduction -> cross-wave LDS -> one atomic/block
    #pragma unroll
    for (int off = 32; off; off >>= 1) acc += __shfl_down(acc, off, 64);
    __shared__ float wsum[4];
    if ((tid & 63) == 0) wsum[tid >> 6] = acc;
    __syncthreads();
    if (tid == 0) atomicAdd(out_sum, wsum[0] + wsum[1] + wsum[2] + wsum[3]);
}

extern "C" void kernel_launch(void* const* d_in, const int* in_sizes, int n_in,
                              void* d_out, int out_size, void* d_ws, size_t ws_size,
                              hipStream_t stream) {
    const float* o = (const float*)d_in[0];
    const float* t = (const float*)d_in[1];
    float* out = (float*)d_out;
    const int n = in_sizes[0];
    const int n_cells = n / 15;
    const int n_groups = n_cells >> 2;
    const int grid = (n_groups + 255) / 256;   // 1568 blocks for the ref shape

    // d_out is poisoned 0xAA before every timed replay -> zero it on-stream.
    hipMemsetAsync(out, 0, sizeof(float), stream);

    yolo_loss_kernel<<<grid, 256, 0, stream>>>(o, t, out, n_cells);
}

// Round 3
// 216.833 us; speedup vs baseline: 1.1568x; 1.1568x over previous
//
#include <hip/hip_runtime.h>

// YOLO loss reduction: B=512, 3136 cells/sample, 15 slots/cell, fp32, sum-reduce.
//
// R1 (LDS tile + barrier): FETCH 94 MB (good) but latency-bound on per-tile
//   vmcnt(0)+barrier drain -> 75 us.
// R2 (cell-per-thread, 240 B lane stride): no barriers but coalescing lost ->
//   FETCH 339 MB (1.76x over-fetch, L3 defeated) -> 116 us.
// R3: slot-decomposed streaming. Thread i consumes float4 #i of both tensors
//   (perfect coalescing, no LDS, no barriers). Per element, the slot s = e%15
//   selects the contribution branch-free; the per-cell gate o[cell*15]!=0 is
//   two scalar gather loads per float4 that hit lines the wave just streamed
//   (L1 hits, ~0 extra HBM). VALU ~8 us << ~30 us memory floor.

#define EPSF 1e-9f

__global__ __launch_bounds__(256) void yolo_loss_kernel(
    const float* __restrict__ o, const float* __restrict__ t,
    float* __restrict__ out_sum, int n4, int n)
{
    const int tid = threadIdx.x;
    const int stride = gridDim.x * 256;
    const float4* o4 = (const float4*)o;
    const float4* t4 = (const float4*)t;

    float acc = 0.f;

    #pragma unroll 2
    for (int i = blockIdx.x * 256 + tid; i < n4; i += stride) {
        const float4 ov = o4[i];
        const float4 tv = t4[i];

        const unsigned e0    = (unsigned)i * 4u;
        const unsigned cell0 = e0 / 15u;               // magic-mul div
        const unsigned slot0 = e0 - cell0 * 15u;
        const unsigned cell3 = (e0 + 3u) / 15u;
        const float g_lo = o[(size_t)cell0 * 15u];     // gate for non-wrapped elems
        const float g_hi = o[(size_t)cell3 * 15u];     // gate after cell boundary

        const float oe[4] = {ov.x, ov.y, ov.z, ov.w};
        const float te[4] = {tv.x, tv.y, tv.z, tv.w};

        #pragma unroll
        for (int j = 0; j < 4; ++j) {
            unsigned s = slot0 + (unsigned)j;
            const bool wrap = s >= 15u;
            s = wrap ? s - 15u : s;
            const float gate = wrap ? g_hi : g_lo;
            const float ox = oe[j], tx = te[j];

            // squared-diff path (sqrt'd for slots 2,3) — inputs are >0 so
            // the always-computed sqrt never produces NaN
            const bool issq = (s == 2u) | (s == 3u);
            const float a = issq ? sqrtf(ox) : ox;
            const float b = issq ? sqrtf(tx) : tx;
            const float d = a - b;
            const float sq = d * d;

            // BCE path (slot 4)
            const float bce = -(tx * __logf(ox + EPSF)
                              + (1.f - tx) * __logf(1.f - ox + EPSF));

            float c = (s == 4u) ? bce : sq;
            c = (s == 1u || s == 14u) ? 0.f : c;
            c = (gate != 0.f) ? c : 0.f;
            acc += c;
        }
    }

    // scalar tail (n % 4) — n is divisible by 4 for the ref shape; kept for safety
    const int tail0 = n4 * 4;
    if (blockIdx.x == 0 && tid < n - tail0) {
        const unsigned e = (unsigned)(tail0 + tid);
        const unsigned cell = e / 15u;
        const unsigned s = e - cell * 15u;
        const float gate = o[(size_t)cell * 15u];
        const float ox = o[e], tx = t[e];
        const bool issq = (s == 2u) | (s == 3u);
        const float a = issq ? sqrtf(ox) : ox;
        const float b = issq ? sqrtf(tx) : tx;
        const float d = a - b;
        const float sq = d * d;
        const float bce = -(tx * __logf(ox + EPSF)
                          + (1.f - tx) * __logf(1.f - ox + EPSF));
        float c = (s == 4u) ? bce : sq;
        c = (s == 1u || s == 14u) ? 0.f : c;
        c = (gate != 0.f) ? c : 0.f;
        acc += c;
    }

    // wave (64-lane) shuffle reduction -> cross-wave LDS -> one atomic/block
    #pragma unroll
    for (int off = 32; off; off >>= 1) acc += __shfl_down(acc, off, 64);
    __shared__ float wsum[4];
    if ((tid & 63) == 0) wsum[tid >> 6] = acc;
    __syncthreads();
    if (tid == 0) atomicAdd(out_sum, wsum[0] + wsum[1] + wsum[2] + wsum[3]);
}

extern "C" void kernel_launch(void* const* d_in, const int* in_sizes, int n_in,
                              void* d_out, int out_size, void* d_ws, size_t ws_size,
                              hipStream_t stream) {
    const float* o = (const float*)d_in[0];
    const float* t = (const float*)d_in[1];
    float* out = (float*)d_out;
    const int n = in_sizes[0];
    const int n4 = n / 4;

    // d_out is poisoned 0xAA before every timed replay -> zero it on-stream.
    hipMemsetAsync(out, 0, sizeof(float), stream);

    // persistent grid: 8 blocks/CU x 256 CUs; grid-stride covers all float4s
    const int grid = 2048;
    yolo_loss_kernel<<<grid, 256, 0, stream>>>(o, t, out, n4, n);
}